// Round 6
// baseline (640.746 us; speedup 1.0000x reference)
//
#include <hip/hip_runtime.h>
#include <math.h>

#define N_NODES 100000
#define N_EDGES 3200000
#define BSHIFT 7
#define BNODES 128                         // nodes per bucket
#define NB 782                             // ceil(N_NODES/128)
#define PLACE_BLOCKS 400

// ---------------------------------------------------------------------------
// gemm1 v2: h[N,16] = x[N,512] @ W1[512,16]
// thread = 1 row x 4 cols; 4 threads/quad share the row's x via width-4
// shuffles (DPP, no LDS, no barriers). 64 rows/block -> 1563 blocks.
// W1 read per-k as one 64B segment/wave-instr (L1-resident).
// ---------------------------------------------------------------------------
__global__ __launch_bounds__(256) void gemm1_kernel(
    const float* __restrict__ x, const float* __restrict__ W1,
    float* __restrict__ h, int nrows)
{
    const int t   = threadIdx.x;
    const int row = blockIdx.x * 64 + (t >> 2);
    const int cg  = t & 3;                  // col group: cols cg*4..cg*4+3
    if (row >= nrows) return;               // whole quads drop together

    const float4* w4 = (const float4*)W1;   // w4[k*4 + cg] = W1[k][cg*4..+4]
    const float4* xr = (const float4*)(x + (size_t)row * 512);

    float4 acc = make_float4(0.f, 0.f, 0.f, 0.f);

    for (int kc4 = 0; kc4 < 128; kc4 += 4) {      // 16 k per iteration
        float4 a = xr[kc4 + cg];                  // my 4 k-values (group kc4+cg)
        #pragma unroll
        for (int g = 0; g < 4; ++g) {
            // broadcast quad-lane g's float4 -> k-group kc4+g (wave-uniform)
            float4 v;
            v.x = __shfl(a.x, g, 4);
            v.y = __shfl(a.y, g, 4);
            v.z = __shfl(a.z, g, 4);
            v.w = __shfl(a.w, g, 4);
            const int kb = (kc4 + g) * 4;         // base k of this group
            float4 w0 = w4[(kb + 0) * 4 + cg];
            float4 w1 = w4[(kb + 1) * 4 + cg];
            float4 w2 = w4[(kb + 2) * 4 + cg];
            float4 w3 = w4[(kb + 3) * 4 + cg];
            acc.x += v.x * w0.x; acc.y += v.x * w0.y;
            acc.z += v.x * w0.z; acc.w += v.x * w0.w;
            acc.x += v.y * w1.x; acc.y += v.y * w1.y;
            acc.z += v.y * w1.z; acc.w += v.y * w1.w;
            acc.x += v.z * w2.x; acc.y += v.z * w2.y;
            acc.z += v.z * w2.z; acc.w += v.z * w2.w;
            acc.x += v.w * w3.x; acc.y += v.w * w3.y;
            acc.z += v.w * w3.z; acc.w += v.w * w3.w;
        }
    }

    *(float4*)(h + (size_t)row * 16 + cg * 4) = acc;
}

// ---------------------------------------------------------------------------
// Binning (unchanged, proven): bucket = dst>>7, packed = src | (dst&127)<<17
// ---------------------------------------------------------------------------
__global__ __launch_bounds__(256) void bin_count_kernel(
    const int* __restrict__ ei, int* __restrict__ bucket_cnt)
{
    __shared__ int hist[NB];
    const int t = threadIdx.x;
    for (int i = t; i < NB; i += 256) hist[i] = 0;
    __syncthreads();
    const int stride = gridDim.x * 256;
    for (int e = blockIdx.x * 256 + t; e < N_EDGES; e += stride)
        atomicAdd(&hist[ei[N_EDGES + e] >> BSHIFT], 1);
    __syncthreads();
    for (int i = t; i < NB; i += 256)
        if (hist[i]) atomicAdd(&bucket_cnt[i], hist[i]);
}

__global__ __launch_bounds__(1024) void bucket_scan_kernel(
    const int* __restrict__ bucket_cnt, int* __restrict__ bucket_base,
    int* __restrict__ bucket_cursor)
{
    __shared__ int s[1024];
    const int t = threadIdx.x;
    s[t] = (t < NB) ? bucket_cnt[t] : 0;
    __syncthreads();
    for (int off = 1; off < 1024; off <<= 1) {
        int v = (t >= off) ? s[t - off] : 0;
        __syncthreads();
        s[t] += v;
        __syncthreads();
    }
    if (t < NB) {
        int excl = (t == 0) ? 0 : s[t - 1];
        bucket_base[t]   = excl;
        bucket_cursor[t] = excl;
        if (t == NB - 1) bucket_base[NB] = s[t];
    }
}

__global__ __launch_bounds__(256) void bin_place_kernel(
    const int* __restrict__ ei, int* __restrict__ bucket_cursor,
    int* __restrict__ packed)
{
    __shared__ int cnt[NB];
    __shared__ int base_off[NB];
    __shared__ int cur[NB];
    const int t = threadIdx.x;
    const int chunk = (N_EDGES + PLACE_BLOCKS - 1) / PLACE_BLOCKS;   // 8000
    const int cs = blockIdx.x * chunk;
    const int ce = min(cs + chunk, N_EDGES);

    for (int i = t; i < NB; i += 256) { cnt[i] = 0; cur[i] = 0; }
    __syncthreads();
    for (int e = cs + t; e < ce; e += 256)
        atomicAdd(&cnt[ei[N_EDGES + e] >> BSHIFT], 1);
    __syncthreads();
    for (int i = t; i < NB; i += 256)
        base_off[i] = cnt[i] ? atomicAdd(&bucket_cursor[i], cnt[i]) : 0;
    __syncthreads();
    for (int e = cs + t; e < ce; e += 256) {
        int s = ei[e];
        int d = ei[N_EDGES + e];
        int b = d >> BSHIFT;
        int pos = base_off[b] + atomicAdd(&cur[b], 1);
        packed[pos] = s | ((d & (BNODES - 1)) << 17);
    }
}

// ---------------------------------------------------------------------------
// csr_sort (unchanged, proven): one block per bucket; counting sort by
// dst_local -> dst-sorted csr_src + row_ptr. Block-local write window.
// ---------------------------------------------------------------------------
__global__ __launch_bounds__(256) void csr_sort_kernel(
    const int* __restrict__ bucket_base, const int* __restrict__ packed,
    int* __restrict__ csr_src, int* __restrict__ row_ptr)
{
    __shared__ int hist[BNODES];
    __shared__ int excl[BNODES];
    __shared__ int cur[BNODES];
    __shared__ int scan[BNODES];
    const int t = threadIdx.x;
    const int b = blockIdx.x;
    if (t < BNODES) { hist[t] = 0; cur[t] = 0; }
    __syncthreads();

    const int bs = bucket_base[b];
    const int be = bucket_base[b + 1];
    for (int e = bs + t; e < be; e += 256)
        atomicAdd(&hist[packed[e] >> 17], 1);
    __syncthreads();

    if (t < BNODES) scan[t] = hist[t];
    __syncthreads();
    for (int off = 1; off < BNODES; off <<= 1) {
        int v = (t < BNODES && t >= off) ? scan[t - off] : 0;
        __syncthreads();
        if (t < BNODES) scan[t] += v;
        __syncthreads();
    }
    if (t < BNODES) {
        int ex = (t == 0) ? 0 : scan[t - 1];
        excl[t] = ex;
        int g = b * BNODES + t;
        if (g < N_NODES) row_ptr[g] = bs + ex;
    }
    if (b == NB - 1 && t == 0) row_ptr[N_NODES] = N_EDGES;
    __syncthreads();

    for (int e = bs + t; e < be; e += 256) {
        int p  = packed[e];
        int dl = p >> 17;
        int pos = bs + excl[dl] + atomicAdd(&cur[dl], 1);
        csr_src[pos] = p & 0x1FFFF;
    }
}

// ---------------------------------------------------------------------------
// gather1 (unchanged): wave per node, 4 edge slots x 16 channels,
// 16 edges/iter; fused +b1 / relu.
// ---------------------------------------------------------------------------
__global__ __launch_bounds__(256) void gather1_kernel(
    const int* __restrict__ row_ptr, const int* __restrict__ csr_src,
    const float* __restrict__ h, const float* __restrict__ b1,
    float* __restrict__ h1)
{
    const int node = (blockIdx.x * 256 + threadIdx.x) >> 6;
    if (node >= N_NODES) return;
    const int lane = threadIdx.x & 63;
    const int c = lane & 15, slot = lane >> 4;
    const int start = row_ptr[node], end = row_ptr[node + 1];

    float acc = 0.f;
    int e = start;
    for (; e + 16 <= end; e += 16) {
        int s0 = csr_src[e + slot * 4 + 0];
        int s1 = csr_src[e + slot * 4 + 1];
        int s2 = csr_src[e + slot * 4 + 2];
        int s3 = csr_src[e + slot * 4 + 3];
        float v0 = h[s0 * 16 + c];
        float v1 = h[s1 * 16 + c];
        float v2 = h[s2 * 16 + c];
        float v3 = h[s3 * 16 + c];
        acc += (v0 + v1) + (v2 + v3);
    }
    for (; e + 4 <= end; e += 4)
        acc += h[csr_src[e + slot] * 16 + c];
    if (e + slot < end)
        acc += h[csr_src[e + slot] * 16 + c];

    acc += __shfl_xor(acc, 16);
    acc += __shfl_xor(acc, 32);
    if (lane < 16)
        h1[(size_t)node * 16 + c] = fmaxf(acc + b1[c], 0.f);
}

// ---------------------------------------------------------------------------
// gather2 + gemm2 + bias + log_softmax, fully in-wave (unchanged).
// ---------------------------------------------------------------------------
__global__ __launch_bounds__(256) void gather2_kernel(
    const int* __restrict__ row_ptr, const int* __restrict__ csr_src,
    const float* __restrict__ h1, const float* __restrict__ W2,
    const float* __restrict__ b2, float* __restrict__ out)
{
    const int node = (blockIdx.x * 256 + threadIdx.x) >> 6;
    if (node >= N_NODES) return;
    const int lane = threadIdx.x & 63;
    const int c = lane & 15, slot = lane >> 4;

    float w2c[16];
    float b2v = 0.f;
    if (lane < 40) {
        b2v = b2[lane];
        #pragma unroll
        for (int k = 0; k < 16; ++k) w2c[k] = W2[k * 40 + lane];
    } else {
        #pragma unroll
        for (int k = 0; k < 16; ++k) w2c[k] = 0.f;
    }

    const int start = row_ptr[node], end = row_ptr[node + 1];
    float acc = 0.f;
    int e = start;
    for (; e + 16 <= end; e += 16) {
        int s0 = csr_src[e + slot * 4 + 0];
        int s1 = csr_src[e + slot * 4 + 1];
        int s2 = csr_src[e + slot * 4 + 2];
        int s3 = csr_src[e + slot * 4 + 3];
        float v0 = h1[s0 * 16 + c];
        float v1 = h1[s1 * 16 + c];
        float v2 = h1[s2 * 16 + c];
        float v3 = h1[s3 * 16 + c];
        acc += (v0 + v1) + (v2 + v3);
    }
    for (; e + 4 <= end; e += 4)
        acc += h1[csr_src[e + slot] * 16 + c];
    if (e + slot < end)
        acc += h1[csr_src[e + slot] * 16 + c];

    acc += __shfl_xor(acc, 16);
    acc += __shfl_xor(acc, 32);

    float z = b2v;
    #pragma unroll
    for (int k = 0; k < 16; ++k)
        z += __shfl(acc, k) * w2c[k];

    float zm = (lane < 40) ? z : -1e30f;
    #pragma unroll
    for (int off = 1; off < 64; off <<= 1)
        zm = fmaxf(zm, __shfl_xor(zm, off));
    float ex = (lane < 40) ? __expf(z - zm) : 0.f;
    float sum = ex;
    #pragma unroll
    for (int off = 1; off < 64; off <<= 1)
        sum += __shfl_xor(sum, off);
    const float lse = zm + __logf(sum);

    if (lane < 40)
        out[(size_t)node * 40 + lane] = z - lse;
}

// ---------------------------------------------------------------------------
extern "C" void kernel_launch(void* const* d_in, const int* in_sizes, int n_in,
                              void* d_out, int out_size, void* d_ws, size_t ws_size,
                              hipStream_t stream)
{
    const float* x  = (const float*)d_in[0];
    const int*   ei = (const int*)d_in[1];
    const float* W1 = (const float*)d_in[2];
    const float* b1 = (const float*)d_in[3];
    const float* W2 = (const float*)d_in[4];
    const float* b2 = (const float*)d_in[5];
    float* out = (float*)d_out;

    // ws (~32.4 MB): h (6.4MB) | csr (12.8MB) | packed (12.8MB, h1 overlays
    // its first 6.4MB after csr_sort) | rowp | bcnt | bbase | bcur
    float* h      = (float*)d_ws;
    int*   csr    = (int*)(h + (size_t)N_NODES * 16);
    int*   packed = csr + N_EDGES;
    float* h1     = (float*)packed;            // packed dead after csr_sort
    int*   rowp   = packed + N_EDGES;
    int*   bcnt   = rowp + (N_NODES + 1);
    int*   bbase  = bcnt + NB;
    int*   bcur   = bbase + (NB + 1);

    const int gemm1_blocks  = (N_NODES + 63) / 64;          // 1563
    const int gather_blocks = (N_NODES + 3) / 4;            // 25000

    hipMemsetAsync(bcnt, 0, NB * sizeof(int), stream);
    bin_count_kernel  <<<256, 256, 0, stream>>>(ei, bcnt);
    bucket_scan_kernel<<<1, 1024, 0, stream>>>(bcnt, bbase, bcur);
    bin_place_kernel  <<<PLACE_BLOCKS, 256, 0, stream>>>(ei, bcur, packed);
    csr_sort_kernel   <<<NB, 256, 0, stream>>>(bbase, packed, csr, rowp);

    gemm1_kernel<<<gemm1_blocks, 256, 0, stream>>>(x, W1, h, N_NODES);

    gather1_kernel<<<gather_blocks, 256, 0, stream>>>(rowp, csr, h, b1, h1);
    gather2_kernel<<<gather_blocks, 256, 0, stream>>>(rowp, csr, h1, W2, b2, out);
}